// Round 2
// baseline (123.990 us; speedup 1.0000x reference)
//
#include <hip/hip_runtime.h>

// SNN forward: T=128, B=8192, I=2, H=256, O=2
//  cur[t,b,h] = x[t,b,0]*W1[h,0] + x[t,b,1]*W1[h,1]
//  scan: reset = (mem>1); mem = 0.9*mem + cur - reset; spk = (mem>1)
//  out[b,o] = (mean of spk over last 10 t) dot W2[o,:]
//
// R12 = R11 post-mortem applied. R11's pk repack cut instructions 1.6x but
// time was identical -> the kernel is FP32-PIPE-WIDTH-bound, not issue-bound
// (gfx950 FP32 peak 157.3 TF == scalar full rate, so v_pk_*_f32 = 4 cyc,
// two 32-wide passes; pk buys issue slots only). Cycle ledger per wave per
// t: R10 = 64x2 = 128; R11 = 24pk*4 + 16*2 + 4movs*2 = 136. Fixes here:
//  1. Weight-pair repack: w01[r] = (W1[h][0], W1[h][1]) contiguous, so
//     pk_mul(xv, w01) = (xa*w0, xc*w1) straight from the loaded float2 pair
//     -- the 4 per-t broadcast movs are gone, and c = fadd(t.x, t.y) is one
//     scalar op. Per pair: 5 pk + 6 scalar = 32 cyc -> 128 cyc/t/wave (-6%).
//     Bitwise-identical roundings (same muls, same add order) -> absmax 0.0.
//  2. Fused epilogue reduce (threadfence-reduction): each block writes its
//     partial, __threadfence (release, L2 wb), lane0 atomicAdd on a per-bg
//     device-global counter; the 8th arriver __threadfence (acquire, inv),
//     then sums partial[hg][b] in ASCENDING hg with the EXACT __fadd_rn
//     chain snn_reduce used -> bit-identical out, second dispatch + launch
//     gap eliminated. Counter self-resets (last block stores 0) so graph
//     replays stay correct; correctness does NOT rely on the XCD swizzle
//     (agent-scope fences handle cross-XCD L2 non-coherence).
//
// Kept from R10/R11: RH=8 chains/thread, saddr-form loads (t*BATCH
// wave-uniform SGPR base + fixed lane voffset), PF=8 rotating prefetch,
// no VGPR clamp, XCD swizzle (bg=blockIdx&127, hg=blockIdx>>7).
//
// Spike-path numerics: per-op fp32 rounding, no FMA; per-element op order
// and epilogue reduction order identical to the absmax-0.0 kernels.
// cnt holds NEGATED counts; x / -10.0f is IEEE-identical to (-x) / 10.0f.

#define T_STEPS 128
#define BATCH   8192
#define HID     256
#define TAIL    10
#define RH      8      // hidden chains per thread
#define NP      (RH/2) // packed pairs per thread
#define LB      64     // batch rows per block (= lanes per wave)
#define NWAVE   4      // waves per block; block covers NWAVE*RH = 32 h
#define HG      8      // h-groups (HID / 32)
#define NBG     (BATCH / LB)   // 128 batch groups
#define PF      8      // prefetch depth (t-steps in flight)

typedef float f32x2 __attribute__((ext_vector_type(2)));

// Packed fp32 VALU ops (VOP3P, IEEE per 32-bit half, 4 cyc/instr on gfx950).
#define PK_MUL(d, a, b) asm("v_pk_mul_f32 %0, %1, %2" : "=v"(d) : "v"(a), "v"(b))
#define PK_ADD(d, a, b) asm("v_pk_add_f32 %0, %1, %2" : "=v"(d) : "v"(a), "v"(b))

// per-bg completion counters: zero-initialized at module load, and the last
// block of each bg stores 0 back -> self-resetting across graph replays.
__device__ unsigned int bg_done[NBG];

__global__ __launch_bounds__(256) void snn_scan(const float* __restrict__ x,
                                                const float* __restrict__ W1,
                                                const float* __restrict__ W2,
                                                float2* __restrict__ partial,
                                                float2* __restrict__ out) {
    const int tid   = threadIdx.x;
    const int lane  = tid & 63;
    const int wave  = tid >> 6;
    const int bg    = blockIdx.x & (NBG - 1);  // same bg -> same XCD for all hg
    const int hg    = blockIdx.x >> 7;
    const int b     = bg * LB + lane;          // batch row (lane part of addr)
    const int hbase = hg * (NWAVE * RH) + wave * RH;

    // W1 row pairs: w01[r] = (W1[h][0], W1[h][1]) for h = hbase + r.
    // Contiguous float2 load; wave-uniform address -> scalarized, one-time.
    f32x2 w01[RH];
    const f32x2* w1v = (const f32x2*)W1;
#pragma unroll
    for (int r = 0; r < RH; ++r) w01[r] = w1v[hbase + r];

    // Uniform-base addressing: xp + t*BATCH is wave-uniform (SGPR base,
    // SALU-stepped); + b is the fixed per-lane voffset.
    const f32x2* xp = (const f32x2*)x;

    f32x2 mem[NP], spkn[NP], cnt[NP];   // spkn, cnt hold NEGATED spikes/counts
#pragma unroll
    for (int p = 0; p < NP; ++p) {
        mem[p]  = f32x2{0.0f, 0.0f};
        spkn[p] = f32x2{0.0f, 0.0f};
        cnt[p]  = f32x2{0.0f, 0.0f};
    }

    const f32x2 k09 = {0.9f, 0.9f};

#define LOADX(t) xp[(size_t)(t) * BATCH + b]

    // Per-element op sequence identical to the scalar absmax-0.0 kernel:
    //   te = (xa*w0_e, xc*w1_e)   [one pk_mul from the loaded (xa,xc) pair]
    //   c  = fadd(te.x, te.y)
    //   mem = ((0.9*mem) + c) + (-spk)       [== sub(add(mul,..), spk)]
    //   spk = (mem > 1)                       [stored negated]
#define STEPP(p)                                                      \
    {                                                                 \
        f32x2 te, to, cc, m1, m2;                                     \
        PK_MUL(te, xv, w01[2 * (p)]);                                 \
        PK_MUL(to, xv, w01[2 * (p) + 1]);                             \
        cc.x = __fadd_rn(te.x, te.y);                                 \
        cc.y = __fadd_rn(to.x, to.y);                                 \
        PK_MUL(m1, k09, mem[p]);                                      \
        PK_ADD(m2, m1, cc);                                           \
        PK_ADD(mem[p], m2, spkn[p]);                                  \
        spkn[p].x = (mem[p].x > 1.0f) ? -1.0f : 0.0f;                 \
        spkn[p].y = (mem[p].y > 1.0f) ? -1.0f : 0.0f;                 \
    }

    // ---- warm-up: fill rotating prefetch buffer with t = 0..7 ----
    f32x2 buf[PF];
#pragma unroll
    for (int j = 0; j < PF; ++j) buf[j] = LOADX(j);

    // ---- main loop: t = 0..111 (14 iters), prefetch t+8 (<= 119) ----
    for (int tb = 0; tb < T_STEPS - 2 * PF; tb += PF) {
#pragma unroll
        for (int j = 0; j < PF; ++j) {
            const f32x2 xv = buf[j];
            buf[j] = LOADX(tb + PF + j);
#pragma unroll
            for (int p = 0; p < NP; ++p) STEPP(p)
        }
    }

    // ---- t = 112..119: consume buf[j], refill with t = 120..127 ----
#pragma unroll
    for (int j = 0; j < PF; ++j) {
        const f32x2 xv = buf[j];
        buf[j] = LOADX(T_STEPS - PF + j);
#pragma unroll
        for (int p = 0; p < NP; ++p) {
            STEPP(p)
            if (j >= PF - 2) PK_ADD(cnt[p], cnt[p], spkn[p]);  // t = 118, 119
        }
    }
    // ---- t = 120..127 (all counted) ----
#pragma unroll
    for (int j = 0; j < PF; ++j) {
        const f32x2 xv = buf[j];
#pragma unroll
        for (int p = 0; p < NP; ++p) {
            STEPP(p)
            PK_ADD(cnt[p], cnt[p], spkn[p]);   // integer-valued, exact in fp32
        }
    }
#undef STEPP
#undef LOADX

    // per-thread partial of out[b, :] over my 8 h (ascending h order).
    // cnt holds -count; x / -10.0f is IEEE-identical to (-x) / 10.0f.
    float p0 = 0.0f, p1 = 0.0f;
#pragma unroll
    for (int p = 0; p < NP; ++p) {
        const float a0 = cnt[p].x / -10.0f;
        p0 = __fadd_rn(p0, __fmul_rn(a0, W2[hbase + 2 * p]));
        p1 = __fadd_rn(p1, __fmul_rn(a0, W2[HID + hbase + 2 * p]));
        const float a1 = cnt[p].y / -10.0f;
        p0 = __fadd_rn(p0, __fmul_rn(a1, W2[hbase + 2 * p + 1]));
        p1 = __fadd_rn(p1, __fmul_rn(a1, W2[HID + hbase + 2 * p + 1]));
    }

    // combine the block's 4 waves (different h-chunks, same b per lane)
    __shared__ float2 red[NWAVE][LB];
    red[wave][lane] = make_float2(p0, p1);
    __syncthreads();
    if (wave == 0) {
        const float2 a0 = red[0][lane], a1 = red[1][lane];
        const float2 a2 = red[2][lane], a3 = red[3][lane];
        float2 s;
        s.x = __fadd_rn(__fadd_rn(a0.x, a1.x), __fadd_rn(a2.x, a3.x));
        s.y = __fadd_rn(__fadd_rn(a0.y, a1.y), __fadd_rn(a2.y, a3.y));
        partial[(size_t)hg * BATCH + b] = s;

        // release: wave0's own stores -> fence covers them (same wave),
        // then signal completion of this hg for this bg.
        __threadfence();
        unsigned int old = 0;
        if (lane == 0) old = atomicAdd(&bg_done[bg], 1u);
        old = (unsigned int)__shfl((int)old, 0);

        if (old == HG - 1) {
            // last sharer of this bg: acquire, then deterministic reduce in
            // ASCENDING hg order -- the exact __fadd_rn chain snn_reduce used.
            __threadfence();
            float sx = 0.0f, sy = 0.0f;
#pragma unroll
            for (int hgi = 0; hgi < HG; ++hgi) {
                const float2 pv = partial[(size_t)hgi * BATCH + b];
                sx = __fadd_rn(sx, pv.x);
                sy = __fadd_rn(sy, pv.y);
            }
            out[b] = make_float2(sx, sy);
            if (lane == 0) bg_done[bg] = 0u;   // self-reset for next replay
        }
    }
}

extern "C" void kernel_launch(void* const* d_in, const int* in_sizes, int n_in,
                              void* d_out, int out_size, void* d_ws, size_t ws_size,
                              hipStream_t stream) {
    const float* x  = (const float*)d_in[0];  // (128, 8192, 2)
    const float* W1 = (const float*)d_in[1];  // (256, 2)
    const float* W2 = (const float*)d_in[2];  // (2, 256)
    float2* out     = (float2*)d_out;         // (8192, 2)
    float2* partial = (float2*)d_ws;          // (8, 8192) float2 = 512 KB scratch

    snn_scan<<<NBG * HG, 256, 0, stream>>>(x, W1, W2, partial, out);
}

// Round 3
// 108.925 us; speedup vs baseline: 1.1383x; 1.1383x over previous
//
#include <hip/hip_runtime.h>

// SNN forward: T=128, B=8192, I=2, H=256, O=2
//  cur[t,b,h] = x[t,b,0]*W1[h,0] + x[t,b,1]*W1[h,1]
//  scan: reset = (mem>1); mem = 0.9*mem + cur - reset; spk = (mem>1)
//  out[b,o] = (mean of spk over last 10 t) dot W2[o,:]
//
// R13. Post-mortems applied:
//  - R12's fused threadfence-reduce REVERTED (+24 us: per-block device-scope
//    fence = L2 wb/inv poisoned concurrent blocks' x streams). Back to the
//    two-dispatch structure.
//  - R11 proved the kernel is FP32-PIPE-WIDTH-bound (pk = 4 cyc): chain work
//    is locked at 128 pipe-cyc/wave/t. Remaining waste is 27% VALU idle =
//    TLP starvation (only 4 waves/SIMD, lockstep vmcnt waits, ramp/drain).
//  - THIS ROUND: RH 8->4, NWAVE 4->8 (512-thread blocks). Same grid (1024),
//    same total pipe work, but 8 waves/SIMD -> stalls covered by TLP.
//    Saddr addressing makes the extra per-wave loads free on the VALU pipe
//    (the R5 "RH=8 wins" result predates saddr; its premise is gone).
//  - Weight-pair repack kept from R12: w01[r]=(W1[h][0],W1[h][1]) contiguous,
//    pk_mul(xv, w01) = (xa*w0, xc*w1) with zero broadcast movs.
//
// Bit-exactness of the epilogue (absmax must stay 0.0): the old tree was
//   per-wave 8-term sequential __fadd_rn chain (ascending h), then
//   (a0+a1)+(a2+a3) over the 4 waves, then ascending-hg chain in snn_reduce.
// With 4 h per thread that tree can't be formed from per-wave partials
// (different association), so threads publish avg[h] to LDS and wave0
// rebuilds the EXACT old chains: c_k = sequential 8-term chain over
// h_local=8k..8k+7, s = (c0+c1)+(c2+c3). snn_reduce unchanged.
//
// Spike-path numerics: per-op fp32 rounding, no FMA; per-element op order
// identical to all absmax-0.0 kernels. spkn/cnt hold NEGATED spikes/counts;
// a+(-1.0) is bitwise a-1.0, and x/-10.0f is IEEE-identical to (-x)/10.0f.

#define T_STEPS 128
#define BATCH   8192
#define HID     256
#define TAIL    10
#define RH      4      // hidden chains per thread
#define NP      (RH/2) // packed pairs per thread
#define LB      64     // batch rows per block (= lanes per wave)
#define NWAVE   8      // waves per block; block covers NWAVE*RH = 32 h
#define HG      8      // h-groups (HID / 32)
#define NBG     (BATCH / LB)   // 128 batch groups
#define PF      8      // prefetch depth (t-steps in flight)

typedef float f32x2 __attribute__((ext_vector_type(2)));

// Packed fp32 VALU ops (VOP3P, IEEE per 32-bit half, 4 cyc/instr on gfx950).
#define PK_MUL(d, a, b) asm("v_pk_mul_f32 %0, %1, %2" : "=v"(d) : "v"(a), "v"(b))
#define PK_ADD(d, a, b) asm("v_pk_add_f32 %0, %1, %2" : "=v"(d) : "v"(a), "v"(b))

__global__ __launch_bounds__(512, 8) void snn_scan(const float* __restrict__ x,
                                                   const float* __restrict__ W1,
                                                   const float* __restrict__ W2,
                                                   float2* __restrict__ partial) {
    const int tid   = threadIdx.x;
    const int lane  = tid & 63;
    const int wave  = tid >> 6;                // 0..7
    const int bg    = blockIdx.x & (NBG - 1);  // same bg -> same XCD for all hg
    const int hg    = blockIdx.x >> 7;         // 0..7
    const int b     = bg * LB + lane;          // batch row (lane part of addr)
    const int hbase = hg * (NWAVE * RH) + wave * RH;

    // W1 row pairs: w01[r] = (W1[h][0], W1[h][1]) for h = hbase + r.
    // Contiguous float2 load; wave-uniform address -> scalarized, one-time.
    f32x2 w01[RH];
    const f32x2* w1v = (const f32x2*)W1;
#pragma unroll
    for (int r = 0; r < RH; ++r) w01[r] = w1v[hbase + r];

    // Uniform-base addressing: xp + t*BATCH is wave-uniform (SGPR base,
    // SALU-stepped); + b is the fixed per-lane voffset.
    const f32x2* xp = (const f32x2*)x;

    f32x2 mem[NP], spkn[NP], cnt[NP];   // spkn, cnt hold NEGATED spikes/counts
#pragma unroll
    for (int p = 0; p < NP; ++p) {
        mem[p]  = f32x2{0.0f, 0.0f};
        spkn[p] = f32x2{0.0f, 0.0f};
        cnt[p]  = f32x2{0.0f, 0.0f};
    }

    const f32x2 k09 = {0.9f, 0.9f};

#define LOADX(t) xp[(size_t)(t) * BATCH + b]

    // Per-element op sequence identical to the scalar absmax-0.0 kernel:
    //   te = (xa*w0_e, xc*w1_e)   [one pk_mul from the loaded (xa,xc) pair]
    //   c  = fadd(te.x, te.y)
    //   mem = ((0.9*mem) + c) + (-spk)       [== sub(add(mul,..), spk)]
    //   spk = (mem > 1)                       [stored negated]
#define STEPP(p)                                                      \
    {                                                                 \
        f32x2 te, to, cc, m1, m2;                                     \
        PK_MUL(te, xv, w01[2 * (p)]);                                 \
        PK_MUL(to, xv, w01[2 * (p) + 1]);                             \
        cc.x = __fadd_rn(te.x, te.y);                                 \
        cc.y = __fadd_rn(to.x, to.y);                                 \
        PK_MUL(m1, k09, mem[p]);                                      \
        PK_ADD(m2, m1, cc);                                           \
        PK_ADD(mem[p], m2, spkn[p]);                                  \
        spkn[p].x = (mem[p].x > 1.0f) ? -1.0f : 0.0f;                 \
        spkn[p].y = (mem[p].y > 1.0f) ? -1.0f : 0.0f;                 \
    }

    // ---- warm-up: fill rotating prefetch buffer with t = 0..7 ----
    f32x2 buf[PF];
#pragma unroll
    for (int j = 0; j < PF; ++j) buf[j] = LOADX(j);

    // ---- main loop: t = 0..111 (14 iters), prefetch t+8 (<= 119) ----
    for (int tb = 0; tb < T_STEPS - 2 * PF; tb += PF) {
#pragma unroll
        for (int j = 0; j < PF; ++j) {
            const f32x2 xv = buf[j];
            buf[j] = LOADX(tb + PF + j);
#pragma unroll
            for (int p = 0; p < NP; ++p) STEPP(p)
        }
    }

    // ---- t = 112..119: consume buf[j], refill with t = 120..127 ----
#pragma unroll
    for (int j = 0; j < PF; ++j) {
        const f32x2 xv = buf[j];
        buf[j] = LOADX(T_STEPS - PF + j);
#pragma unroll
        for (int p = 0; p < NP; ++p) {
            STEPP(p)
            if (j >= PF - 2) PK_ADD(cnt[p], cnt[p], spkn[p]);  // t = 118, 119
        }
    }
    // ---- t = 120..127 (all counted) ----
#pragma unroll
    for (int j = 0; j < PF; ++j) {
        const f32x2 xv = buf[j];
#pragma unroll
        for (int p = 0; p < NP; ++p) {
            STEPP(p)
            PK_ADD(cnt[p], cnt[p], spkn[p]);   // integer-valued, exact in fp32
        }
    }
#undef STEPP
#undef LOADX

    // Publish per-h tail averages; wave0 rebuilds the exact R10/R11 tree.
    // cnt holds -count; x / -10.0f is IEEE-identical to (-x) / 10.0f.
    __shared__ float avgs[NWAVE * RH][LB];    // 32 x 64 floats = 8 KB
#pragma unroll
    for (int p = 0; p < NP; ++p) {
        avgs[wave * RH + 2 * p][lane]     = cnt[p].x / -10.0f;
        avgs[wave * RH + 2 * p + 1][lane] = cnt[p].y / -10.0f;
    }
    __syncthreads();

    if (wave == 0) {
        // c_k = sequential 8-term __fadd_rn chain over h_local = 8k..8k+7
        // (== old wave-k per-thread chain), then (c0+c1)+(c2+c3).
        float c0[4], c1[4];
#pragma unroll
        for (int k = 0; k < 4; ++k) {
            float s0 = 0.0f, s1 = 0.0f;
#pragma unroll
            for (int j = 0; j < 8; ++j) {
                const int hl = 8 * k + j;
                const float a = avgs[hl][lane];
                s0 = __fadd_rn(s0, __fmul_rn(a, W2[hg * 32 + hl]));
                s1 = __fadd_rn(s1, __fmul_rn(a, W2[HID + hg * 32 + hl]));
            }
            c0[k] = s0; c1[k] = s1;
        }
        float2 s;
        s.x = __fadd_rn(__fadd_rn(c0[0], c0[1]), __fadd_rn(c0[2], c0[3]));
        s.y = __fadd_rn(__fadd_rn(c1[0], c1[1]), __fadd_rn(c1[2], c1[3]));
        partial[(size_t)hg * BATCH + b] = s;
    }
}

// sum the 8 h-group partials -> out[b, 0:2] (ascending hg, exact chain)
__global__ __launch_bounds__(256) void snn_reduce(const float2* __restrict__ partial,
                                                  float2* __restrict__ out) {
    const int b = blockIdx.x * 256 + threadIdx.x;   // 8192 threads
    float sx = 0.0f, sy = 0.0f;
#pragma unroll
    for (int hg = 0; hg < HG; ++hg) {
        const float2 p = partial[(size_t)hg * BATCH + b];
        sx = __fadd_rn(sx, p.x);
        sy = __fadd_rn(sy, p.y);
    }
    out[b] = make_float2(sx, sy);
}

extern "C" void kernel_launch(void* const* d_in, const int* in_sizes, int n_in,
                              void* d_out, int out_size, void* d_ws, size_t ws_size,
                              hipStream_t stream) {
    const float* x  = (const float*)d_in[0];  // (128, 8192, 2)
    const float* W1 = (const float*)d_in[1];  // (256, 2)
    const float* W2 = (const float*)d_in[2];  // (2, 256)
    float2* out     = (float2*)d_out;         // (8192, 2)
    float2* partial = (float2*)d_ws;          // (8, 8192) float2 = 512 KB scratch

    snn_scan<<<NBG * HG, 512, 0, stream>>>(x, W1, W2, partial);
    snn_reduce<<<BATCH / 256, 256, 0, stream>>>(partial, out);
}